// Round 6
// baseline (4338.132 us; speedup 1.0000x reference)
//
#include <hip/hip_runtime.h>

#define BATCH   64
#define TSTEPS  256
#define NINPUT  512
#define HDIM    1024
#define G4      4096   // 4*HDIM
#define NWG     64     // scan workgroups
#define NHC     16     // h-columns owned per scan WG

typedef __attribute__((ext_vector_type(8))) short short8;
typedef __attribute__((ext_vector_type(4))) float f32x4;
typedef __attribute__((ext_vector_type(4))) unsigned int u32x4;
typedef __attribute__((ext_vector_type(2))) unsigned int u32x2;

static __device__ __forceinline__ unsigned short f2bf(float x) {
    unsigned u = __float_as_uint(x);
    unsigned r = 0x7fffu + ((u >> 16) & 1u);
    return (unsigned short)((u + r) >> 16);
}
static __device__ __forceinline__ float bf2f(unsigned short b) {
    return __uint_as_float(((unsigned)b) << 16);
}
static __device__ __forceinline__ float sigf(float x) {
    return 1.f / (1.f + __expf(-x));
}
static __device__ __forceinline__ float tanhf_fast(float x) {
    return 2.f / (1.f + __expf(-2.f * x)) - 1.f;   // graceful at +/-inf
}

// ---------------- poison ring with bf16-NaN sentinel ----------------
__global__ void k_poison(u32x4* __restrict__ p, long n4) {
    long i = (long)blockIdx.x * blockDim.x + threadIdx.x;
    long st = (long)gridDim.x * blockDim.x;
    u32x4 v = (u32x4){0xFFFFFFFFu, 0xFFFFFFFFu, 0xFFFFFFFFu, 0xFFFFFFFFu};
    for (; i < n4; i += st) p[i] = v;
}

// ---------------- float -> bf16 conversion (vectorized, grid-stride) ----------------
__global__ void k_f2b(const float* __restrict__ in, unsigned short* __restrict__ out, long n) {
    long i = (long)blockIdx.x * blockDim.x + threadIdx.x;
    long stride = (long)gridDim.x * blockDim.x;
    for (long j = i * 4; j < n; j += stride * 4) {
        float4 v = *reinterpret_cast<const float4*>(in + j);
        ushort4 o;
        o.x = f2bf(v.x); o.y = f2bf(v.y); o.z = f2bf(v.z); o.w = f2bf(v.w);
        *reinterpret_cast<ushort4*>(out + j) = o;
    }
}

// ---------------- bias combine + h0 init ----------------
__global__ void k_prep_small(const float* __restrict__ bih0, const float* __restrict__ bhh0,
                             const float* __restrict__ bih1, const float* __restrict__ bhh1,
                             float* __restrict__ bb0, float* __restrict__ bb1,
                             const float* __restrict__ h0,
                             unsigned short* __restrict__ hA0, unsigned short* __restrict__ hA1) {
    int i = blockIdx.x * blockDim.x + threadIdx.x;
    if (i < G4) { bb0[i] = bih0[i] + bhh0[i]; bb1[i] = bih1[i] + bhh1[i]; }
    if (i < BATCH * HDIM) {
        hA0[i] = f2bf(h0[i]);
        hA1[i] = f2bf(h0[BATCH * HDIM + i]);
    }
}

// ---------------- bf16 MFMA GEMM: C[M,N] = A[M,K] * B[N,K]^T + bias[N] ----------------
#define BM 128
#define BN 128
#define BK 64

static __device__ __forceinline__ void g2l16(const unsigned short* g, void* lds) {
    __builtin_amdgcn_global_load_lds(
        (const __attribute__((address_space(1))) unsigned int*)g,
        (__attribute__((address_space(3))) unsigned int*)lds, 16, 0, 0);
}

__global__ __launch_bounds__(256)
void k_gemm_bt(const unsigned short* __restrict__ A,   // [M,K] bf16 bits
               const unsigned short* __restrict__ B,   // [N,K] bf16 bits
               const float* __restrict__ bias,         // [N]
               unsigned short* __restrict__ C,         // [M,N] bf16
               int M, int N, int K)
{
    __shared__ unsigned short As[BM * BK];  // XOR-swizzled rows of 128B
    __shared__ unsigned short Bs[BN * BK];
    const int tid = threadIdx.x;
    const int lane = tid & 63, wv = tid >> 6;
    const int nbn = N / BN;
    const int bm0 = (blockIdx.x / nbn) * BM;
    const int bn0 = (blockIdx.x % nbn) * BN;
    const int wr = wv >> 1, wc = wv & 1;   // 2x2 wave grid, each wave 64x64

    f32x4 acc[4][4];
#pragma unroll
    for (int i = 0; i < 4; i++)
#pragma unroll
        for (int j = 0; j < 4; j++) acc[i][j] = (f32x4){0.f, 0.f, 0.f, 0.f};

    const int srow = tid >> 3;          // staging row (per issue of 32 rows)
    const int scb  = (tid & 7) * 16;    // staging byte-col within 128B row

    for (int kt = 0; kt < K; kt += BK) {
        __syncthreads();
#pragma unroll
        for (int is = 0; is < 4; is++) {
            int row = is * 32 + srow;
            int kb = scb ^ ((row & 7) << 4);          // pre-swizzled global source
            g2l16(A + (size_t)(bm0 + row) * K + kt + (kb >> 1),
                  (char*)As + is * 4096 + wv * 1024);
        }
#pragma unroll
        for (int is = 0; is < 4; is++) {
            int row = is * 32 + srow;
            int kb = scb ^ ((row & 7) << 4);
            g2l16(B + (size_t)(bn0 + row) * K + kt + (kb >> 1),
                  (char*)Bs + is * 4096 + wv * 1024);
        }
        asm volatile("s_waitcnt vmcnt(0)" ::: "memory");
        __syncthreads();

#pragma unroll
        for (int ks = 0; ks < 2; ks++) {
            short8 a[4], b[4];
            const int kb = ks * 64 + ((lane >> 4) << 4);
#pragma unroll
            for (int mt = 0; mt < 4; mt++) {
                int r = wr * 64 + mt * 16 + (lane & 15);
                a[mt] = *reinterpret_cast<const short8*>(
                    (const char*)As + r * 128 + (kb ^ ((r & 7) << 4)));
            }
#pragma unroll
            for (int nt = 0; nt < 4; nt++) {
                int n = wc * 64 + nt * 16 + (lane & 15);
                b[nt] = *reinterpret_cast<const short8*>(
                    (const char*)Bs + n * 128 + (kb ^ ((n & 7) << 4)));
            }
#pragma unroll
            for (int mt = 0; mt < 4; mt++)
#pragma unroll
                for (int nt = 0; nt < 4; nt++)
                    acc[mt][nt] = __builtin_amdgcn_mfma_f32_16x16x32_bf16(
                        a[mt], b[nt], acc[mt][nt], 0, 0, 0);
        }
    }

    // epilogue: + bias, store bf16
#pragma unroll
    for (int nt = 0; nt < 4; nt++) {
        int cg = bn0 + wc * 64 + nt * 16 + (lane & 15);
        float bv = bias[cg];
#pragma unroll
        for (int mt = 0; mt < 4; mt++) {
#pragma unroll
            for (int e = 0; e < 4; e++) {
                int rg = bm0 + wr * 64 + mt * 16 + ((lane >> 4) << 2) + e;
                C[(size_t)rg * N + cg] = f2bf(acc[mt][nt][e] + bv);
            }
        }
    }
}

// ---------------- persistent LSTM scan, barrier-free (data-as-flag ring) ----------------
// 64 WGs x 256 thr. WG g owns h-cols [16g,16g+16) -> 64 gate rows (i,f,g,o x 16).
// Weights persist in registers; waves split K (256 each); partials reduced in LDS.
// h sequence lives in ring[B][T][H] (bf16), PRE-POISONED to 0xFFFF (bf16 NaN).
// Consumers load slot t-1 with sc0/sc1 into registers and validate those exact
// registers in plain C after a single vmcnt(0): packed u32 >= 0xFFFF0000 <=>
// sentinel (real |h| <= 1 so hi-half <= 0xBF80). On failure: sleep + re-issue.
// MFMA runs only after validation (separate basic block: no hoist hazard).
// Producers never wait. Dword-granularity store atomicity makes mixed
// sentinel/real halves within one dword impossible.
__global__ __launch_bounds__(256, 1)
void k_scan(const unsigned short* __restrict__ whh,   // [4096][1024] bf16
            const unsigned short* __restrict__ xw,    // [B*T][4096] bf16 (x-proj + biases)
            const float* __restrict__ c0,             // [64][1024] fp32 (this layer's slice)
            const unsigned short* __restrict__ h0b,   // [64][1024] bf16 initial h
            unsigned short* __restrict__ ring,        // [64][T][1024] bf16, poisoned
            float* __restrict__ hn, float* __restrict__ cn)  // [64][1024] fp32 outputs
{
    const int tid = threadIdx.x;
    const int lane = tid & 63, kw = tid >> 6;     // wave index = K-slice
    const int colbase = blockIdx.x * NHC;

    __shared__ float plds[4][64][34];             // [wave][batch-row][2 gates x 16 + pad]

    // --- persistent B-fragments: 4 gates x 16 cols, this wave's K-slice (256) ---
    short8 bfr[4][8];
    {
        const int c = lane & 15;
#pragma unroll
        for (int g = 0; g < 4; g++) {
            int grow = g * HDIM + colbase + c;       // gate g, owned col c
#pragma unroll
            for (int s = 0; s < 8; s++) {
                int k = kw * 256 + s * 32 + ((lane >> 4) << 3);
                bfr[g][s] = *reinterpret_cast<const short8*>(whh + (size_t)grow * HDIM + k);
            }
        }
    }

    // --- c state: thread owns batch row r2, cols u0..u0+3 ---
    const int r2 = tid >> 2;
    const int u0 = (tid & 3) * 4;
    f32x4 cst = *reinterpret_cast<const f32x4*>(c0 + (size_t)r2 * HDIM + colbase + u0);

    const int arow = lane & 15;
    const size_t koff = (size_t)kw * 256 + ((lane >> 4) << 3);

    for (int t = 0; t < TSTEPS; t++) {
        // ---- xw loads: plain C (compiler-managed waits), issued early ----
        const unsigned short* xp = xw + ((size_t)r2 * TSTEPS + t) * G4 + colbase + u0;
        const u32x2 xi = *reinterpret_cast<const u32x2*>(xp);
        const u32x2 xf = *reinterpret_cast<const u32x2*>(xp + HDIM);
        const u32x2 xg = *reinterpret_cast<const u32x2*>(xp + 2 * HDIM);
        const u32x2 xo = *reinterpret_cast<const u32x2*>(xp + 3 * HDIM);

        // ---- A-fragment base pointers (t=0: h0 buffer; else ring slot t-1) ----
        const unsigned short* pa0;
        size_t rs;
        if (t == 0) {
            pa0 = h0b + (size_t)arow * HDIM + koff;
            rs = (size_t)16 * HDIM;
        } else {
            pa0 = ring + ((size_t)arow * TSTEPS + (t - 1)) * HDIM + koff;
            rs = (size_t)16 * TSTEPS * HDIM;
        }
        const unsigned short* pa1 = pa0 + rs;
        const unsigned short* pa2 = pa0 + 2 * rs;
        const unsigned short* pa3 = pa0 + 3 * rs;

        // ---- load + validate, retry until sentinel-free (no speculation) ----
        u32x4 afr[8][4];
        for (;;) {
#define ISSUE4(S, OFFS) \
            asm volatile("global_load_dwordx4 %0, %1, off offset:" OFFS " sc0 sc1" : "=v"(afr[S][0]) : "v"(pa0)); \
            asm volatile("global_load_dwordx4 %0, %1, off offset:" OFFS " sc0 sc1" : "=v"(afr[S][1]) : "v"(pa1)); \
            asm volatile("global_load_dwordx4 %0, %1, off offset:" OFFS " sc0 sc1" : "=v"(afr[S][2]) : "v"(pa2)); \
            asm volatile("global_load_dwordx4 %0, %1, off offset:" OFFS " sc0 sc1" : "=v"(afr[S][3]) : "v"(pa3));
            ISSUE4(0, "0")   ISSUE4(1, "64")  ISSUE4(2, "128") ISSUE4(3, "192")
            ISSUE4(4, "256") ISSUE4(5, "320") ISSUE4(6, "384") ISSUE4(7, "448")
#undef ISSUE4
            asm volatile("s_waitcnt vmcnt(0)" ::: "memory");
            __builtin_amdgcn_sched_barrier(0);

            unsigned mx = 0;
#pragma unroll
            for (int s = 0; s < 8; s++)
#pragma unroll
                for (int m = 0; m < 4; m++) {
                    u32x4 u = afr[s][m];
                    unsigned a = u[0] > u[1] ? u[0] : u[1];
                    unsigned b = u[2] > u[3] ? u[2] : u[3];
                    unsigned c = a > b ? a : b;
                    mx = mx > c ? mx : c;
                }
            if (!__any(mx >= 0xFFFF0000u)) break;   // all real -> consume
            __builtin_amdgcn_s_sleep(1);
        }

        // ---- MFMA (validated registers only) ----
        f32x4 acc[4][4];
#pragma unroll
        for (int m = 0; m < 4; m++)
#pragma unroll
            for (int g = 0; g < 4; g++) acc[m][g] = (f32x4){0.f, 0.f, 0.f, 0.f};
#pragma unroll
        for (int s = 0; s < 8; s++)
#pragma unroll
            for (int m = 0; m < 4; m++) {
                short8 av = __builtin_bit_cast(short8, afr[s][m]);
#pragma unroll
                for (int g = 0; g < 4; g++)
                    acc[m][g] = __builtin_amdgcn_mfma_f32_16x16x32_bf16(
                        av, bfr[g][s], acc[m][g], 0, 0, 0);
            }

        // ---- pass A: partials for gates i,f -> LDS -> reduce ----
#pragma unroll
        for (int m = 0; m < 4; m++)
#pragma unroll
            for (int g = 0; g < 2; g++) {
                int col = g * 16 + (lane & 15);
                int rb = m * 16 + ((lane >> 4) << 2);
#pragma unroll
                for (int e = 0; e < 4; e++)
                    plds[kw][rb + e][col] = acc[m][g][e];
            }
        __syncthreads();
        f32x4 sI = (f32x4){0.f,0.f,0.f,0.f}, sF = sI;
#pragma unroll
        for (int w = 0; w < 4; w++) {
            sI += *reinterpret_cast<const f32x4*>(&plds[w][r2][u0]);
            sF += *reinterpret_cast<const f32x4*>(&plds[w][r2][16 + u0]);
        }
        __syncthreads();
        // ---- pass B: partials for gates g,o ----
#pragma unroll
        for (int m = 0; m < 4; m++)
#pragma unroll
            for (int g = 2; g < 4; g++) {
                int col = (g - 2) * 16 + (lane & 15);
                int rb = m * 16 + ((lane >> 4) << 2);
#pragma unroll
                for (int e = 0; e < 4; e++)
                    plds[kw][rb + e][col] = acc[m][g][e];
            }
        __syncthreads();
        f32x4 sG = (f32x4){0.f,0.f,0.f,0.f}, sO = sG;
#pragma unroll
        for (int w = 0; w < 4; w++) {
            sG += *reinterpret_cast<const f32x4*>(&plds[w][r2][u0]);
            sO += *reinterpret_cast<const f32x4*>(&plds[w][r2][16 + u0]);
        }
        __syncthreads();   // plds reusable next step

        // ---- add xw, pointwise LSTM cell (4 values/thread) ----
#define ADDX(S, V) { unsigned lo = V[0], hi = V[1]; \
        S[0] += bf2f((unsigned short)lo); S[1] += bf2f((unsigned short)(lo >> 16)); \
        S[2] += bf2f((unsigned short)hi); S[3] += bf2f((unsigned short)(hi >> 16)); }
        ADDX(sI, xi) ADDX(sF, xf) ADDX(sG, xg) ADDX(sO, xo)
#undef ADDX

        float hv[4];
#pragma unroll
        for (int j = 0; j < 4; j++) {
            float c = sigf(sF[j]) * cst[j] + sigf(sI[j]) * tanhf_fast(sG[j]);
            cst[j] = c;
            hv[j] = sigf(sO[j]) * tanhf_fast(c);
        }
        u32x2 hp;
        hp[0] = (unsigned)f2bf(hv[0]) | ((unsigned)f2bf(hv[1]) << 16);
        hp[1] = (unsigned)f2bf(hv[2]) | ((unsigned)f2bf(hv[3]) << 16);
        unsigned short* wp = ring + ((size_t)r2 * TSTEPS + t) * HDIM + colbase + u0;
        asm volatile("global_store_dwordx2 %0, %1, off sc0 sc1"
                     :: "v"(wp), "v"(hp) : "memory");   // the store IS the signal

        if (t == TSTEPS - 1) {
            const size_t hi_ = (size_t)r2 * HDIM + colbase + u0;
            *reinterpret_cast<f32x4*>(hn + hi_) = (f32x4){hv[0], hv[1], hv[2], hv[3]};
            *reinterpret_cast<f32x4*>(cn + hi_) = cst;
        }
    }
}

// ---------------- decode + log_softmax ----------------
__global__ __launch_bounds__(256)
void k_decode(const float* __restrict__ h1,    // [64][1024] fp32 (hn layer 1)
              const float* __restrict__ wdec,  // [512][1024]
              const float* __restrict__ bdec,  // [512]
              float* __restrict__ out)         // [64][512]
{
    __shared__ float hs[HDIM];
    __shared__ float ls[NINPUT];
    __shared__ float red[256];
    const int r = blockIdx.x, tid = threadIdx.x;
    reinterpret_cast<float4*>(hs)[tid] = reinterpret_cast<const float4*>(h1 + (size_t)r * HDIM)[tid];
    __syncthreads();
#pragma unroll
    for (int rep = 0; rep < 2; rep++) {
        int n = tid + rep * 256;
        float s = bdec[n];
        const float4* w4 = reinterpret_cast<const float4*>(wdec + (size_t)n * HDIM);
        for (int k = 0; k < HDIM / 4; k++) {
            float4 w = w4[k];
            float4 h4 = reinterpret_cast<const float4*>(hs)[k];
            s += w.x * h4.x + w.y * h4.y + w.z * h4.z + w.w * h4.w;
        }
        ls[n] = s;
    }
    __syncthreads();
    red[tid] = fmaxf(ls[tid], ls[tid + 256]);
    __syncthreads();
    for (int s2 = 128; s2 > 0; s2 >>= 1) {
        if (tid < s2) red[tid] = fmaxf(red[tid], red[tid + s2]);
        __syncthreads();
    }
    float M = red[0];
    __syncthreads();
    red[tid] = __expf(ls[tid] - M) + __expf(ls[tid + 256] - M);
    __syncthreads();
    for (int s2 = 128; s2 > 0; s2 >>= 1) {
        if (tid < s2) red[tid] += red[tid + s2];
        __syncthreads();
    }
    float lse = M + __logf(red[0]);
    out[(size_t)r * NINPUT + tid] = ls[tid] - lse;
    out[(size_t)r * NINPUT + tid + 256] = ls[tid + 256] - lse;
}

// ---------------- host launcher ----------------
extern "C" void kernel_launch(void* const* d_in, const int* in_sizes, int n_in,
                              void* d_out, int out_size, void* d_ws, size_t ws_size,
                              hipStream_t stream)
{
    const float* x    = (const float*)d_in[0];
    const float* h0   = (const float*)d_in[1];
    const float* c0   = (const float*)d_in[2];
    const float* wih0 = (const float*)d_in[3];
    const float* whh0 = (const float*)d_in[4];
    const float* bih0 = (const float*)d_in[5];
    const float* bhh0 = (const float*)d_in[6];
    const float* wih1 = (const float*)d_in[7];
    const float* whh1 = (const float*)d_in[8];
    const float* bih1 = (const float*)d_in[9];
    const float* bhh1 = (const float*)d_in[10];
    const float* wdec = (const float*)d_in[11];
    const float* bdec = (const float*)d_in[12];
    float* out = (float*)d_out;

    char* ws = (char*)d_ws;
    size_t off = 0;
    auto alloc = [&](size_t bytes) -> void* {
        void* p = ws + off;
        off += (bytes + 255) & ~(size_t)255;
        return p;
    };
    // Layout keeps peak footprint ~214 MB: ring1 overlays the xb/w0ib/w0hb
    // region (+4.1 MB of w1ib), which is dead by the time scan1 runs
    // (poisoned after gemm1). NOTE: no backslash at end of comments!
    unsigned short* xw    = (unsigned short*)alloc((size_t)BATCH * TSTEPS * G4 * 2);      // 134.2 MB
    unsigned short* ring0 = (unsigned short*)alloc((size_t)BATCH * TSTEPS * HDIM * 2);    // 33.5 MB (= out0)
    unsigned short* w1hb  = (unsigned short*)alloc((size_t)G4 * HDIM * 2);                // 8.4 MB
    float*          bb1   = (float*)alloc(G4 * 4);
    unsigned short* hA1   = (unsigned short*)alloc(BATCH * HDIM * 2);
    unsigned short* xb    = (unsigned short*)alloc((size_t)BATCH * TSTEPS * NINPUT * 2);  // 16.8 MB (ring1 overlay)
    unsigned short* w0ib  = (unsigned short*)alloc((size_t)G4 * NINPUT * 2);              // 4.2 MB  (ring1 overlay)
    unsigned short* w0hb  = (unsigned short*)alloc((size_t)G4 * HDIM * 2);                // 8.4 MB  (ring1 overlay)
    unsigned short* w1ib  = (unsigned short*)alloc((size_t)G4 * HDIM * 2);                // 8.4 MB  (partial overlay)
    float*          bb0   = (float*)alloc(G4 * 4);
    unsigned short* hA0   = (unsigned short*)alloc(BATCH * HDIM * 2);
    unsigned short* ring1 = xb;   // overlays xb+w0ib+w0hb+(4.1 MB of w1ib): 33.5 MB span

    const long ring_n4 = (long)BATCH * TSTEPS * HDIM * 2 / 16;

    // poison ring0 (replay safety: previous launch left real values in it)
    k_poison<<<2048, 256, 0, stream>>>((u32x4*)ring0, ring_n4);

    k_f2b<<<1024, 256, 0, stream>>>(x, xb, (long)BATCH * TSTEPS * NINPUT);
    k_f2b<<<512, 256, 0, stream>>>(wih0, w0ib, (long)G4 * NINPUT);
    k_f2b<<<1024, 256, 0, stream>>>(whh0, w0hb, (long)G4 * HDIM);
    k_f2b<<<1024, 256, 0, stream>>>(wih1, w1ib, (long)G4 * HDIM);
    k_f2b<<<1024, 256, 0, stream>>>(whh1, w1hb, (long)G4 * HDIM);
    k_prep_small<<<512, 256, 0, stream>>>(bih0, bhh0, bih1, bhh1, bb0, bb1, h0, hA0, hA1);

    const int M = BATCH * TSTEPS;
    // layer 0 input projection: xw = xb @ wih0^T + (bih0+bhh0)
    k_gemm_bt<<<(M / BM) * (G4 / BN), 256, 0, stream>>>(xb, w0ib, bb0, xw, M, G4, NINPUT);
    // layer 0 scan (ring0 doubles as out0 = [B][T][H] h-sequence)
    k_scan<<<NWG, 256, 0, stream>>>(w0hb, xw, c0, hA0, ring0,
                                    out + 32768,
                                    out + 32768 + 2 * BATCH * HDIM);
    // layer 1 input projection: xw = out0 @ wih1^T + (bih1+bhh1)
    k_gemm_bt<<<(M / BM) * (G4 / BN), 256, 0, stream>>>(ring0, w1ib, bb1, xw, M, G4, HDIM);
    // poison ring1 (xb/w0ib/w0hb/w1ib all dead now)
    k_poison<<<2048, 256, 0, stream>>>((u32x4*)ring1, ring_n4);
    // layer 1 scan
    k_scan<<<NWG, 256, 0, stream>>>(w1hb, xw, c0 + BATCH * HDIM, hA1, ring1,
                                    out + 32768 + BATCH * HDIM,
                                    out + 32768 + 2 * BATCH * HDIM + BATCH * HDIM);
    // decode from fp32 final h of layer 1 (already in d_out)
    k_decode<<<BATCH, 256, 0, stream>>>(out + 32768 + BATCH * HDIM, wdec, bdec, out);
}